// Round 9
// baseline (408.273 us; speedup 1.0000x reference)
//
#include <hip/hip_runtime.h>

#define T_    128
#define B_    64
#define H_    2048
#define L_    4
#define C_    10
#define BN_EPS 1e-5f
#define K0REAL 144
#define K0PAD  192   // padded to multiple of 64 so layer-0 uses gemm_bf16_8ph

typedef __attribute__((ext_vector_type(8))) short bf16x8;
typedef __attribute__((ext_vector_type(4))) float f32x4;

__device__ __forceinline__ short f2bf(float f) {
    union { float f; unsigned u; } v; v.f = f;
    unsigned r = (v.u + 0x7FFFu + ((v.u >> 16) & 1u)) >> 16;
    return (short)r;
}
__device__ __forceinline__ float bf2f(short s) {
    union { unsigned u; float f; } v; v.u = ((unsigned)(unsigned short)s) << 16;
    return v.f;
}
__device__ __forceinline__ void gload16(const short* g, short* l) {
    __builtin_amdgcn_global_load_lds(
        (const __attribute__((address_space(1))) void*)g,
        (__attribute__((address_space(3))) void*)l, 16, 0, 0);
}

#define SBAR() do { __builtin_amdgcn_sched_barrier(0); \
                    __builtin_amdgcn_s_barrier();      \
                    __builtin_amdgcn_sched_barrier(0); } while (0)

// ---------------------------------------------------------------------------
// 256x256 / BK=64 / 8-wave GEMM, 4 phases per K-tile, ONE barrier per phase.
// Zb[M,N](bf16) = A[M,Kb](bf16) @ Bw[N,Kb](bf16)^T + bias
// XCD-chunked block map. Counted vmcnt(8) once per K-tile.
// Grid must be (M/256, 8) = 256 blocks; Kb % 64 == 0, Kb/64 >= 2.
// [verified rounds 5-8; frozen]
// ---------------------------------------------------------------------------
__global__ __launch_bounds__(512, 2) void gemm_bf16_8ph(
    const short* __restrict__ A, const short* __restrict__ Bw,
    const float* __restrict__ bias, short* __restrict__ Zb,
    int M, int N, int Kb)
{
    __shared__ short As[2][256 * 64];
    __shared__ short Bs[2][256 * 64];

    const int tid  = threadIdx.x;
    const int wid  = tid >> 6;
    const int lane = tid & 63;

    const int lin = blockIdx.y * gridDim.x + blockIdx.x;
    const int xcd = lin & 7;
    const int loc = lin >> 3;
    const int m0  = (xcd * 4 + (loc & 3)) * 256;
    const int n0  = (loc >> 2) * 256;

    const int wm  = (wid >> 2) * 128;
    const int wn  = (wid & 3) * 64;

    const int fr  = lane & 15;
    const int fq  = lane >> 4;
    const int fr7 = fr & 7;

    const int s_sub   = wid * 2;
    const int s_rowi  = lane >> 3;
    const int s_chunk = (lane & 7) ^ s_rowi;

    auto stA = [&](int kt, int h, int i) {
        const int r = h * 128 + (s_sub + i) * 8 + s_rowi;
        gload16(A + (size_t)(m0 + r) * Kb + kt * 64 + s_chunk * 8,
                &As[kt & 1][h * 8192 + (s_sub + i) * 512 + lane * 8]);
    };
    auto stB = [&](int kt, int h, int i) {
        const int r = h * 128 + (s_sub + i) * 8 + s_rowi;
        gload16(Bw + (size_t)(n0 + r) * Kb + kt * 64 + s_chunk * 8,
                &Bs[kt & 1][h * 8192 + (s_sub + i) * 512 + lane * 8]);
    };
    auto rdA = [&](int buf, int m, int kk) -> bf16x8 {
        const int ar = wm + m * 16 + fr;
        const int slot = (kk * 4 + fq) ^ fr7;
        return *(const bf16x8*)&As[buf][ar * 64 + slot * 8];
    };
    auto rdB = [&](int buf, int n, int kk) -> bf16x8 {
        const int br = wn + n * 16 + fr;
        const int slot = (kk * 4 + fq) ^ fr7;
        return *(const bf16x8*)&Bs[buf][br * 64 + slot * 8];
    };

    f32x4 acc[8][4];
#pragma unroll
    for (int m = 0; m < 8; ++m)
#pragma unroll
        for (int n = 0; n < 4; ++n)
            acc[m][n] = (f32x4){0.f, 0.f, 0.f, 0.f};

    const int NK = Kb >> 6;

    stA(0, 0, 0); stA(0, 0, 1); stA(0, 1, 0); stA(0, 1, 1);
    stB(0, 0, 0); stB(0, 0, 1); stB(0, 1, 0); stB(0, 1, 1);
    stA(1, 0, 0); stA(1, 0, 1); stA(1, 1, 0); stA(1, 1, 1);
    stB(1, 0, 0); stB(1, 0, 1); stB(1, 1, 0); stB(1, 1, 1);
    asm volatile("s_waitcnt vmcnt(8)" ::: "memory");
    SBAR();

    bf16x8 aF[4][2], b0[2][2], b1[2][2];

#pragma unroll 1
    for (int g = 0; g < NK; ++g) {
        const int buf = g & 1;
        // ---- P1: rd A m0-3 + B n0-1; MFMA (m0-3, n0-1) -------------------
#pragma unroll
        for (int m = 0; m < 4; ++m)
#pragma unroll
            for (int kk = 0; kk < 2; ++kk) aF[m][kk] = rdA(buf, m, kk);
#pragma unroll
        for (int n = 0; n < 2; ++n)
#pragma unroll
            for (int kk = 0; kk < 2; ++kk) b0[n][kk] = rdB(buf, n, kk);
        __builtin_amdgcn_s_setprio(1);
#pragma unroll
        for (int m = 0; m < 4; ++m)
#pragma unroll
            for (int n = 0; n < 2; ++n)
#pragma unroll
                for (int kk = 0; kk < 2; ++kk)
                    acc[m][n] = __builtin_amdgcn_mfma_f32_16x16x32_bf16(
                        aF[m][kk], b0[n][kk], acc[m][n], 0, 0, 0);
        __builtin_amdgcn_s_setprio(0);
        SBAR();
        // ---- P2: rd B n2-3; MFMA (m0-3, n2-3) ----------------------------
#pragma unroll
        for (int n = 0; n < 2; ++n)
#pragma unroll
            for (int kk = 0; kk < 2; ++kk) b1[n][kk] = rdB(buf, n + 2, kk);
        __builtin_amdgcn_s_setprio(1);
#pragma unroll
        for (int m = 0; m < 4; ++m)
#pragma unroll
            for (int n = 0; n < 2; ++n)
#pragma unroll
                for (int kk = 0; kk < 2; ++kk)
                    acc[m][n + 2] = __builtin_amdgcn_mfma_f32_16x16x32_bf16(
                        aF[m][kk], b1[n][kk], acc[m][n + 2], 0, 0, 0);
        __builtin_amdgcn_s_setprio(0);
        SBAR();
        // ---- P3: rd A m4-7; stage B(g+2); MFMA (m4-7, n2-3) --------------
#pragma unroll
        for (int m = 0; m < 4; ++m)
#pragma unroll
            for (int kk = 0; kk < 2; ++kk) aF[m][kk] = rdA(buf, m + 4, kk);
        if (g + 2 < NK) { stB(g + 2, 0, 0); stB(g + 2, 0, 1);
                          stB(g + 2, 1, 0); stB(g + 2, 1, 1); }
        __builtin_amdgcn_s_setprio(1);
#pragma unroll
        for (int m = 0; m < 4; ++m)
#pragma unroll
            for (int n = 0; n < 2; ++n)
#pragma unroll
                for (int kk = 0; kk < 2; ++kk)
                    acc[m + 4][n + 2] = __builtin_amdgcn_mfma_f32_16x16x32_bf16(
                        aF[m][kk], b1[n][kk], acc[m + 4][n + 2], 0, 0, 0);
        __builtin_amdgcn_s_setprio(0);
        SBAR();
        // ---- P4: stage A(g+2); MFMA (m4-7, n0-1); counted vmcnt ----------
        if (g + 2 < NK) { stA(g + 2, 0, 0); stA(g + 2, 0, 1);
                          stA(g + 2, 1, 0); stA(g + 2, 1, 1); }
        __builtin_amdgcn_s_setprio(1);
#pragma unroll
        for (int m = 0; m < 4; ++m)
#pragma unroll
            for (int n = 0; n < 2; ++n)
#pragma unroll
                for (int kk = 0; kk < 2; ++kk)
                    acc[m + 4][n] = __builtin_amdgcn_mfma_f32_16x16x32_bf16(
                        aF[m][kk], b0[n][kk], acc[m + 4][n], 0, 0, 0);
        __builtin_amdgcn_s_setprio(0);
        if (g + 2 < NK) asm volatile("s_waitcnt vmcnt(8)" ::: "memory");
        else            asm volatile("s_waitcnt vmcnt(0)" ::: "memory");
        SBAR();
    }

    // epilogue: D map col=lane&15, row=(lane>>4)*4+r; bf16 out
#pragma unroll
    for (int m = 0; m < 8; ++m) {
#pragma unroll
        for (int n = 0; n < 4; ++n) {
            const int col = n0 + wn + n * 16 + fr;
            const float bsum = bias[col];
#pragma unroll
            for (int r = 0; r < 4; ++r) {
                const int row = m0 + wm + m * 16 + fq * 4 + r;
                Zb[(size_t)row * N + col] = f2bf(acc[m][n][r] + bsum);
            }
        }
    }
}

// ---------------------------------------------------------------------------
// IndRNN scan v5: 1 thread per (b,h); 8-deep chunked register prefetch.
// ---------------------------------------------------------------------------
__global__ __launch_bounds__(256) void scan_bf16_v5(
    const short* __restrict__ Zb, const float* __restrict__ u,
    short* __restrict__ Hb, float* __restrict__ sum, float* __restrict__ sumsq,
    int store_all)
{
    const int idx = blockIdx.x * blockDim.x + threadIdx.x;   // b*H + h
    const int h = idx & (H_ - 1);
    const float uu = u[h];
    const int stride = B_ * H_;
    float hp = 0.f, s1 = 0.f, s2 = 0.f;

    short zr[8];
#pragma unroll
    for (int j = 0; j < 8; ++j) zr[j] = Zb[(size_t)j * stride + idx];

#pragma unroll 1
    for (int t0 = 0; t0 < T_; t0 += 8) {
        short cur[8];
#pragma unroll
        for (int j = 0; j < 8; ++j) cur[j] = zr[j];
        if (t0 + 8 < T_) {
#pragma unroll
            for (int j = 0; j < 8; ++j)
                zr[j] = Zb[(size_t)(t0 + 8 + j) * stride + idx];
        }
#pragma unroll
        for (int j = 0; j < 8; ++j) {
            float hv = fmaxf(bf2f(cur[j]) + uu * hp, 0.f);
            hp = hv;
            s1 += hv;
            s2 += hv * hv;
            if (store_all) Hb[(size_t)(t0 + j) * stride + idx] = f2bf(hv);
        }
    }
    if (!store_all) Hb[(size_t)(T_ - 1) * stride + idx] = f2bf(hp);

    atomicAdd(&sum[h], s1);
    atomicAdd(&sumsq[h], s2);
}

// ---------------------------------------------------------------------------
// Fused BN-finalize + fold:
//   scale/shift computed from raw stats into LDS (once per block), then
//   Wb[n,k] = bf16(W[n,k]*scale[k]); bias2[n] = b[n] + sum_k shift[k]*W[n,k].
// One wave per row; grid = H*64/256 blocks.
// ---------------------------------------------------------------------------
__global__ __launch_bounds__(256) void fold_wb_f(
    const float* __restrict__ Wf,
    const float* __restrict__ sum, const float* __restrict__ sumsq,
    const float* __restrict__ gamma, const float* __restrict__ beta,
    const float* __restrict__ b,
    short* __restrict__ Wb, float* __restrict__ bias2)
{
    __shared__ float s_sc[H_];
    __shared__ float s_sh[H_];
    const int tid = threadIdx.x;
    const float inv_n = 1.f / (float)(T_ * B_);
    for (int h = tid; h < H_; h += 256) {
        const float m = sum[h] * inv_n;
        const float v = sumsq[h] * inv_n - m * m;
        const float s = gamma[h] * rsqrtf(v + BN_EPS);
        s_sc[h] = s;
        s_sh[h] = beta[h] - m * s;
    }
    __syncthreads();

    const int wrow = (blockIdx.x * blockDim.x + tid) >> 6;
    const int lane = tid & 63;
    const float* wr = Wf + (size_t)wrow * H_;
    short* wb = Wb + (size_t)wrow * H_;
    float acc = 0.f;
    for (int k4 = lane * 4; k4 < H_; k4 += 256) {
        float4 w  = *(const float4*)(wr + k4);
        float4 sc = *(const float4*)&s_sc[k4];
        float4 sh = *(const float4*)&s_sh[k4];
        short4 s;
        s.x = f2bf(w.x * sc.x); s.y = f2bf(w.y * sc.y);
        s.z = f2bf(w.z * sc.z); s.w = f2bf(w.w * sc.w);
        *(short4*)(wb + k4) = s;
        acc += w.x * sh.x + w.y * sh.y + w.z * sh.z + w.w * sh.w;
    }
#pragma unroll
    for (int o = 32; o > 0; o >>= 1) acc += __shfl_down(acc, o);
    if (lane == 0) bias2[wrow] = acc + b[wrow];
}

// ---------------------------------------------------------------------------
// Merged conversion (x + W0 -> bf16 padded to K0PAD) + BN-stat zeroing.
// ---------------------------------------------------------------------------
__global__ __launch_bounds__(256) void conv_pad2z(
    const float* __restrict__ X, const float* __restrict__ W0,
    short* __restrict__ Xb, short* __restrict__ W0b,
    float* __restrict__ stats /* 8*H_ floats to zero */)
{
    const int npr = K0PAD / 4;   // 48
    const int total = (T_ * B_ + H_) * npr;
    const int idx = blockIdx.x * blockDim.x + threadIdx.x;
    if (idx < 8 * H_) stats[idx] = 0.f;
    if (idx >= total) return;
    const int r = idx / npr;
    const int c4 = (idx - r * npr) * 4;
    const float* src;
    short* dst;
    if (r < T_ * B_) { src = X + (size_t)r * K0REAL;              dst = Xb + (size_t)r * K0PAD; }
    else             { src = W0 + (size_t)(r - T_ * B_) * K0REAL; dst = W0b + (size_t)(r - T_ * B_) * K0PAD; }
    short4 s = {0, 0, 0, 0};
    if (c4 < K0REAL) {
        float4 v = *(const float4*)(src + c4);
        s.x = f2bf(v.x); s.y = f2bf(v.y); s.z = f2bf(v.z); s.w = f2bf(v.w);
    }
    *(short4*)(dst + c4) = s;
}

// ---------------------------------------------------------------------------
// Fused finalize + final projection:
// out[b,c] = sum_h (bf2f(Hb[b,h])*scale[h]+shift[h]) * Wlast[c,h] + blast[c]
// scale/shift computed inline from raw stats. One wave per (b,c).
// ---------------------------------------------------------------------------
__global__ __launch_bounds__(256) void final_proj_f(
    const short* __restrict__ Hb,
    const float* __restrict__ sum, const float* __restrict__ sumsq,
    const float* __restrict__ gamma, const float* __restrict__ beta,
    const float* __restrict__ Wlast, const float* __restrict__ blast,
    float* __restrict__ out)
{
    const int wave = (blockIdx.x * blockDim.x + threadIdx.x) >> 6;
    const int lane = threadIdx.x & 63;
    if (wave >= B_ * C_) return;
    const int b = wave / C_;
    const int c = wave % C_;
    const float inv_n = 1.f / (float)(T_ * B_);
    float acc = 0.f;
    for (int h = lane; h < H_; h += 64) {
        const float m = sum[h] * inv_n;
        const float v = sumsq[h] * inv_n - m * m;
        const float s = gamma[h] * rsqrtf(v + BN_EPS);
        const float sh = beta[h] - m * s;
        const float hv = bf2f(Hb[(size_t)b * H_ + h]) * s + sh;
        acc += hv * Wlast[(size_t)c * H_ + h];
    }
#pragma unroll
    for (int o = 32; o > 0; o >>= 1) acc += __shfl_down(acc, o);
    if (lane == 0) out[(size_t)b * C_ + c] = acc + blast[c];
}

// ---------------------------------------------------------------------------
extern "C" void kernel_launch(void* const* d_in, const int* in_sizes, int n_in,
                              void* d_out, int out_size, void* d_ws, size_t ws_size,
                              hipStream_t stream)
{
    const float* x      = (const float*)d_in[0];  // [8192,144]
    const float* W0     = (const float*)d_in[1];  // [2048,144]
    const float* Ws     = (const float*)d_in[2];  // [3,2048,2048]
    const float* bs     = (const float*)d_in[3];  // [4,2048]
    const float* us     = (const float*)d_in[4];
    const float* gammas = (const float*)d_in[5];
    const float* betas  = (const float*)d_in[6];
    const float* Wlast  = (const float*)d_in[7];  // [10,2048]
    const float* blast  = (const float*)d_in[8];
    float* out = (float*)d_out;

    char* ws = (char*)d_ws;
    short* zb      = (short*)ws;                            // 32 MB bf16 z
    short* Ab      = (short*)(ws + (size_t)32 * 1048576);   // 32 MB bf16 h
    short* Wb      = (short*)(ws + (size_t)64 * 1048576);   // 8 MB folded W
    short* X0b     = (short*)(ws + (size_t)72 * 1048576);   // 3.1 MB (8192x192)
    short* W0b     = (short*)(ws + (size_t)76 * 1048576);   // 0.79 MB (2048x192)
    float* sums    = (float*)(ws + (size_t)78 * 1048576);   // [4][H] sums
    float* sumsqs  = sums + 4 * H_;                         // [4][H] sumsq
    float* bias2   = sumsqs + 4 * H_;

    const int M = T_ * B_;   // 8192
    const dim3 g256(M / 256, H_ / 256);   // (32, 8) = 256 blocks

    // conversion + stats zeroing (one dispatch)
    conv_pad2z<<<((M + H_) * (K0PAD / 4) + 255) / 256, 256, 0, stream>>>(
        x, W0, X0b, W0b, sums);

    // layer 0 projection (K padded to 192) via the same pipelined kernel
    gemm_bf16_8ph<<<g256, 512, 0, stream>>>(X0b, W0b, bs, zb, M, H_, K0PAD);

    for (int l = 0; l < L_; ++l) {
        scan_bf16_v5<<<(B_ * H_) / 256, 256, 0, stream>>>(
            zb, us + l * H_, Ab, sums + l * H_, sumsqs + l * H_,
            (l < L_ - 1) ? 1 : 0);
        if (l < L_ - 1) {
            const float* Wl = Ws + (size_t)l * H_ * H_;
            fold_wb_f<<<(H_ * 64) / 256, 256, 0, stream>>>(
                Wl, sums + l * H_, sumsqs + l * H_,
                gammas + l * H_, betas + l * H_,
                bs + (l + 1) * H_, Wb, bias2);
            gemm_bf16_8ph<<<g256, 512, 0, stream>>>(Ab, Wb, bias2, zb, M, H_, H_);
        }
    }

    final_proj_f<<<(B_ * C_ * 64 + 255) / 256, 256, 0, stream>>>(
        Ab + (size_t)(T_ - 1) * B_ * H_, sums + 3 * H_, sumsqs + 3 * H_,
        gammas + 3 * H_, betas + 3 * H_, Wlast, blast, out);
}